// Round 10
// baseline (181.966 us; speedup 1.0000x reference)
//
#include <hip/hip_runtime.h>
#include <hip/hip_bf16.h>
#include <math.h>

// Problem constants
#define B_   64
#define N_   256
#define DV_  2048
#define DP_  8
#define DT_  768
#define DF_  512
#define DK_  2056   // DV + DP

// Workspace layout (floats):
#define WS_S  32768    // S[B][DP]   = 512
#define WS_C  33280    // c[B]       = 64
#define WS_V  33344    // v[B][DK]   = 131584

// ---------------------------------------------------------------------------
// Kernel AB (fused): one block per batch b (64 blocks).
//  1) stage text[b,0,:] in LDS
//  2) w[f] = gelu(text@Wt + bt)[f] * Wa[f] into LDS (full 512 per block)
//  3) S[b] (position column sums), c[b] = bo.w + ba
//  4) v[b][k] = sum_f Wo[k,f] * w[f] for all 2056 k  (w in registers,
//     8 k per round x 32 f-lanes, shuffle-reduce over lane bits 0..4)
// ---------------------------------------------------------------------------
__global__ __launch_bounds__(256) void kAB(
    const float* __restrict__ pos,   // [B][N][DP]
    const float* __restrict__ text,  // [B][N][DT]
    const float* __restrict__ Wt,    // [DT][DF]
    const float* __restrict__ bt,    // [DF]
    const float* __restrict__ Wo,    // [DK][DF]
    const float* __restrict__ bo,    // [DF]
    const float* __restrict__ ba,    // [1]
    const float* __restrict__ Wa,    // [DF]
    float* __restrict__ S,           // [B][DP]
    float* __restrict__ c,           // [B]
    float* __restrict__ v)           // [B][DK]
{
    const int b = blockIdx.x;
    const int t = threadIdx.x;

    __shared__ float  tx[DT_];        // 3 KB
    __shared__ float4 swW[2][128];    // 4 KB  [kc][fq]
    __shared__ float  wls[DF_];       // 2 KB
    __shared__ float  red[256];       // 1 KB
    __shared__ float  spos[32][DP_];  // 1 KB

    // 1) stage text[b,0,:] (192 float4)
    if (t < 192)
        ((float4*)tx)[t] = ((const float4*)(text + (size_t)b * N_ * DT_))[t];

    // 3a) position column sums: thread (g = t>>3, d = t&7), 8 rows each
    {
        const int d = t & 7, g = t >> 3;
        float s = 0.f;
        #pragma unroll
        for (int i = 0; i < 8; ++i)
            s += pos[(size_t)b * N_ * DP_ + (g + 32 * i) * DP_ + d];
        spos[g][d] = s;
    }
    __syncthreads();
    if (t < DP_) {
        float s = 0.f;
        #pragma unroll
        for (int g = 0; g < 32; ++g) s += spos[g][t];
        S[b * DP_ + t] = s;
    }

    // 2) w phase: thread (fq = t&127 -> f0 = 4*fq, kc = t>>7 -> 384-k half)
    {
        const int fq = t & 127;
        const int kc = t >> 7;
        const int f0 = fq * 4;
        float4 acc = make_float4(0.f, 0.f, 0.f, 0.f);
        const int kb = kc * 384;
        #pragma unroll 8
        for (int j = 0; j < 384; ++j) {
            const int k = kb + j;
            const float x = tx[k];
            const float4 wv = *(const float4*)(Wt + (size_t)k * DF_ + f0);
            acc.x = fmaf(x, wv.x, acc.x);
            acc.y = fmaf(x, wv.y, acc.y);
            acc.z = fmaf(x, wv.z, acc.z);
            acc.w = fmaf(x, wv.w, acc.w);
        }
        swW[kc][fq] = acc;
    }
    __syncthreads();
    if (t < 128) {
        const float4 p0 = swW[0][t];
        const float4 p1 = swW[1][t];
        const float sv[4] = {p0.x + p1.x, p0.y + p1.y, p0.z + p1.z, p0.w + p1.w};
        #pragma unroll
        for (int cc = 0; cc < 4; ++cc) {
            const int f = 4 * t + cc;
            const float z = sv[cc] + bt[f];
            const float ge = 0.5f * z * (1.f + erff(z * 0.70710678118654752f));
            wls[f] = ge * Wa[f];
        }
    }
    __syncthreads();

    // 3b) c[b] = ba + sum_f bo[f]*w[f]
    red[t] = bo[t] * wls[t] + bo[t + 256] * wls[t + 256];
    __syncthreads();
    #pragma unroll
    for (int s2 = 128; s2 > 0; s2 >>= 1) {
        if (t < s2) red[t] += red[t + s2];
        __syncthreads();
    }
    if (t == 0) c[b] = red[0] + ba[0];

    // 4) v phase: kk = t>>5 (8 k's per round), ff = t&31 (16 f's each).
    // w for this thread's f-slice loaded ONCE into registers.
    const int kk = t >> 5;
    const int ff = t & 31;
    float4 w0, w1, w2, w3;
    {
        const float4* wq = (const float4*)wls + ff * 4;
        w0 = wq[0]; w1 = wq[1]; w2 = wq[2]; w3 = wq[3];
    }
    const float* wbase = Wo + (size_t)kk * DF_ + ff * 16;
    float* vout = v + (size_t)b * DK_;

    for (int r = 0; r < 257; ++r) {
        const int k = r * 8 + kk;
        const float* wrow = wbase + (size_t)r * 8 * DF_;
        const float4 o0 = *(const float4*)(wrow);
        const float4 o1 = *(const float4*)(wrow + 4);
        const float4 o2 = *(const float4*)(wrow + 8);
        const float4 o3 = *(const float4*)(wrow + 12);
        float a = 0.f;
        a = fmaf(o0.x, w0.x, a); a = fmaf(o0.y, w0.y, a);
        a = fmaf(o0.z, w0.z, a); a = fmaf(o0.w, w0.w, a);
        a = fmaf(o1.x, w1.x, a); a = fmaf(o1.y, w1.y, a);
        a = fmaf(o1.z, w1.z, a); a = fmaf(o1.w, w1.w, a);
        a = fmaf(o2.x, w2.x, a); a = fmaf(o2.y, w2.y, a);
        a = fmaf(o2.z, w2.z, a); a = fmaf(o2.w, w2.w, a);
        a = fmaf(o3.x, w3.x, a); a = fmaf(o3.y, w3.y, a);
        a = fmaf(o3.z, w3.z, a); a = fmaf(o3.w, w3.w, a);
        // reduce over ff (lane bits 0..4)
        a += __shfl_xor(a, 1, 64);
        a += __shfl_xor(a, 2, 64);
        a += __shfl_xor(a, 4, 64);
        a += __shfl_xor(a, 8, 64);
        a += __shfl_xor(a, 16, 64);
        if (ff == 0) vout[k] = a;
    }
}

// ---------------------------------------------------------------------------
// Kernel C (unchanged, ~7us L3-bound): 2 rows per wave, 2048 blocks.
// out[b,i] = visual[b,i,:].v1[b] + 257*pos[b,i,:].v2[b] - S[b].v2[b] + c[b]
// ---------------------------------------------------------------------------
__global__ __launch_bounds__(256) void kC(
    const float* __restrict__ visual, // [B][N][DV]
    const float* __restrict__ pos,    // [B][N][DP]
    const float* __restrict__ v,      // [B][DK]
    const float* __restrict__ S,      // [B][DP]
    const float* __restrict__ c,      // [B]
    float* __restrict__ out)          // [B][N]
{
    const int t    = threadIdx.x;
    const int wave = t >> 6;
    const int lane = t & 63;
    const int R0   = blockIdx.x * 8 + wave * 2;
    const int b    = R0 >> 8;
    const int i0   = R0 & 255;

    const float4* vb = (const float4*)(v + (size_t)b * DK_);
    const float4* v0 = (const float4*)(visual + ((size_t)b * N_ + i0) * DV_);

    float a0 = 0.f, a1 = 0.f;
    #pragma unroll
    for (int j = 0; j < 8; ++j) {
        const int idx = lane + 64 * j;
        const float4 wv = vb[idx];
        const float4 x0 = v0[idx];
        const float4 x1 = v0[idx + 512];
        a0 = fmaf(x0.x, wv.x, a0); a0 = fmaf(x0.y, wv.y, a0);
        a0 = fmaf(x0.z, wv.z, a0); a0 = fmaf(x0.w, wv.w, a0);
        a1 = fmaf(x1.x, wv.x, a1); a1 = fmaf(x1.y, wv.y, a1);
        a1 = fmaf(x1.z, wv.z, a1); a1 = fmaf(x1.w, wv.w, a1);
    }
    #pragma unroll
    for (int off = 1; off < 64; off <<= 1) {
        a0 += __shfl_xor(a0, off, 64);
        a1 += __shfl_xor(a1, off, 64);
    }

    if (lane < 2) {
        const float accq = (lane == 0) ? a0 : a1;
        const int i = i0 + lane;
        const float* v2 = v + (size_t)b * DK_ + DV_;
        const float* pr = pos + ((size_t)b * N_ + i) * DP_;
        const float* Sb = S + b * DP_;
        float pd = 0.f, sd = 0.f;
        #pragma unroll
        for (int d = 0; d < DP_; ++d) {
            pd = fmaf(pr[d], v2[d], pd);
            sd = fmaf(Sb[d], v2[d], sd);
        }
        out[(size_t)b * N_ + i] = accq + 257.f * pd - sd + c[b];
    }
}

// ---------------------------------------------------------------------------
extern "C" void kernel_launch(void* const* d_in, const int* in_sizes, int n_in,
                              void* d_out, int out_size, void* d_ws, size_t ws_size,
                              hipStream_t stream) {
    const float* visual   = (const float*)d_in[0];
    const float* position = (const float*)d_in[1];
    const float* text     = (const float*)d_in[2];
    const float* Wt       = (const float*)d_in[3];
    const float* bt       = (const float*)d_in[4];
    const float* Wo       = (const float*)d_in[5];
    const float* bo       = (const float*)d_in[6];
    const float* Wa       = (const float*)d_in[7];
    const float* ba       = (const float*)d_in[8];
    float* out = (float*)d_out;

    float* ws = (float*)d_ws;
    float* S  = ws + WS_S;
    float* c  = ws + WS_C;
    float* v  = ws + WS_V;

    kAB<<<B_, 256, 0, stream>>>(position, text, Wt, bt, Wo, bo, ba, Wa, S, c, v);
    kC<<<2048, 256, 0, stream>>>(visual, position, v, S, c, out);
}

// Round 11
// 62.011 us; speedup vs baseline: 2.9344x; 2.9344x over previous
//
#include <hip/hip_runtime.h>
#include <hip/hip_bf16.h>
#include <math.h>

// Problem constants
#define B_   64
#define N_   256
#define DV_  2048
#define DP_  8
#define DT_  768
#define DF_  512
#define DK_  2056   // DV + DP

// Workspace layout (floats):
#define WS_WT 0        // wT[DF][B]  = 32768
#define WS_S  32768    // S[B][DP]   = 512
#define WS_C  33280    // c[B]       = 64
#define WS_V  33344    // v[B][DK]   = 131584

// ---------------------------------------------------------------------------
// Kernel A (R3-exact): w[b,f] = gelu(text@Wt+bt)*Wa -> wT[f][b]; S[b].
// grid = 256 blocks: b = blk>>2, g = blk&3 (128-f slice).
// ---------------------------------------------------------------------------
__global__ __launch_bounds__(256) void kA(
    const float* __restrict__ pos,   // [B][N][DP]
    const float* __restrict__ text,  // [B][N][DT]
    const float* __restrict__ Wt,    // [DT][DF]
    const float* __restrict__ bt,    // [DF]
    const float* __restrict__ Wa,    // [DF]
    float* __restrict__ wT,          // [DF][B]
    float* __restrict__ S)           // [B][DP]
{
    const int b = blockIdx.x >> 2;
    const int g = blockIdx.x & 3;
    const int t = threadIdx.x;
    const int a = t & 31;
    const int kh = t >> 5;

    __shared__ float tx[DT_];
    __shared__ float4 sred[8][32];
    __shared__ float spos[32][DP_];

    for (int k = t; k < DT_; k += 256)
        tx[k] = text[(size_t)b * N_ * DT_ + k];

    {
        const int d = t & 7, gi = t >> 3;
        float s = 0.f;
        for (int i = gi; i < N_; i += 32)
            s += pos[(size_t)b * N_ * DP_ + i * DP_ + d];
        spos[gi][d] = s;
    }
    __syncthreads();

    if (t < DP_) {
        float s = 0.f;
        #pragma unroll
        for (int gi = 0; gi < 32; ++gi) s += spos[gi][t];
        if (g == 0) S[b * DP_ + t] = s;
    }

    const int f0 = g * 128 + 4 * a;
    float4 acc = make_float4(0.f, 0.f, 0.f, 0.f);
    const int kbase = kh * 96;
    for (int j = 0; j < 96; ++j) {
        const int k = kbase + j;
        const float x = tx[k];
        const float4 wv = *(const float4*)(Wt + (size_t)k * DF_ + f0);
        acc.x = fmaf(x, wv.x, acc.x);
        acc.y = fmaf(x, wv.y, acc.y);
        acc.z = fmaf(x, wv.z, acc.z);
        acc.w = fmaf(x, wv.w, acc.w);
    }
    sred[kh][a] = acc;
    __syncthreads();

    if (t < 32) {
        float4 s = sred[0][t];
        #pragma unroll
        for (int h = 1; h < 8; ++h) {
            const float4 p = sred[h][t];
            s.x += p.x; s.y += p.y; s.z += p.z; s.w += p.w;
        }
        const float sv[4] = {s.x, s.y, s.z, s.w};
        #pragma unroll
        for (int cc = 0; cc < 4; ++cc) {
            const int f = g * 128 + 4 * t + cc;
            const float z = sv[cc] + bt[f];
            const float ge = 0.5f * z * (1.f + erff(z * 0.70710678118654752f));
            wT[(size_t)f * B_ + b] = ge * Wa[f];
        }
    }
}

// ---------------------------------------------------------------------------
// Kernel B (R3-exact): v[b,k] = sum_f Wo[k,f]*w[b,f]. Blocks 0..513: 4 k-rows
// each; block 514: c[b].
// ---------------------------------------------------------------------------
__global__ __launch_bounds__(256) void kB(
    const float* __restrict__ Wo,    // [DK][DF]
    const float* __restrict__ bo,    // [DF]
    const float* __restrict__ ba,    // [1]
    const float* __restrict__ wT,    // [DF][B]
    float* __restrict__ v,           // [B][DK]
    float* __restrict__ c)           // [B]
{
    const int t = threadIdx.x;
    __shared__ float  wo[4][DF_];
    __shared__ float4 red[4][16][16];
    __shared__ float  sbo[DF_];
    __shared__ float4 cred[16][16];

    if (blockIdx.x < 514) {
        const int k0 = blockIdx.x * 4;
        {
            const float4* src = (const float4*)(Wo + (size_t)k0 * DF_);
            float4*       dst = (float4*)wo;
            dst[t]       = src[t];
            dst[t + 256] = src[t + 256];
        }
        __syncthreads();

        const int bq = t & 15;
        const int fg = t >> 4;
        float4 acc0 = make_float4(0.f, 0.f, 0.f, 0.f);
        float4 acc1 = acc0, acc2 = acc0, acc3 = acc0;
        const int fbase = fg * 32;
        #pragma unroll 4
        for (int j = 0; j < 32; ++j) {
            const int f = fbase + j;
            const float4 wv = *(const float4*)(wT + (size_t)f * B_ + 4 * bq);
            const float s0 = wo[0][f], s1 = wo[1][f], s2 = wo[2][f], s3 = wo[3][f];
            acc0.x = fmaf(s0, wv.x, acc0.x); acc0.y = fmaf(s0, wv.y, acc0.y);
            acc0.z = fmaf(s0, wv.z, acc0.z); acc0.w = fmaf(s0, wv.w, acc0.w);
            acc1.x = fmaf(s1, wv.x, acc1.x); acc1.y = fmaf(s1, wv.y, acc1.y);
            acc1.z = fmaf(s1, wv.z, acc1.z); acc1.w = fmaf(s1, wv.w, acc1.w);
            acc2.x = fmaf(s2, wv.x, acc2.x); acc2.y = fmaf(s2, wv.y, acc2.y);
            acc2.z = fmaf(s2, wv.z, acc2.z); acc2.w = fmaf(s2, wv.w, acc2.w);
            acc3.x = fmaf(s3, wv.x, acc3.x); acc3.y = fmaf(s3, wv.y, acc3.y);
            acc3.w = fmaf(s3, wv.w, acc3.w); acc3.z = fmaf(s3, wv.z, acc3.z);
        }
        red[0][fg][bq] = acc0;
        red[1][fg][bq] = acc1;
        red[2][fg][bq] = acc2;
        red[3][fg][bq] = acc3;
        __syncthreads();
        if (t < 64) {
            const int r = t >> 4, bq2 = t & 15;
            float4 s = red[r][0][bq2];
            #pragma unroll
            for (int g = 1; g < 16; ++g) {
                const float4 p = red[r][g][bq2];
                s.x += p.x; s.y += p.y; s.z += p.z; s.w += p.w;
            }
            const float sv[4] = {s.x, s.y, s.z, s.w};
            #pragma unroll
            for (int cc = 0; cc < 4; ++cc)
                v[(size_t)(4 * bq2 + cc) * DK_ + k0 + r] = sv[cc];
        }
    } else {
        for (int k = t; k < DF_; k += 256) sbo[k] = bo[k];
        __syncthreads();
        const int bq = t & 15;
        const int fh = t >> 4;
        float4 acc = make_float4(0.f, 0.f, 0.f, 0.f);
        for (int j = 0; j < 32; ++j) {
            const int f = fh * 32 + j;
            const float s = sbo[f];
            const float4 wv = *(const float4*)(wT + (size_t)f * B_ + 4 * bq);
            acc.x = fmaf(s, wv.x, acc.x);
            acc.y = fmaf(s, wv.y, acc.y);
            acc.z = fmaf(s, wv.z, acc.z);
            acc.w = fmaf(s, wv.w, acc.w);
        }
        cred[fh][bq] = acc;
        __syncthreads();
        if (fh == 0) {
            float4 s = cred[0][bq];
            #pragma unroll
            for (int h = 1; h < 16; ++h) {
                const float4 p = cred[h][bq];
                s.x += p.x; s.y += p.y; s.z += p.z; s.w += p.w;
            }
            const float sv[4] = {s.x, s.y, s.z, s.w};
            #pragma unroll
            for (int cc = 0; cc < 4; ++cc)
                c[4 * bq + cc] = sv[cc] + ba[0];
        }
    }
}

// ---------------------------------------------------------------------------
// Kernel C (R3-exact): 2 rows per wave, 2048 blocks (8/CU, 32 waves/CU).
// out[b,i] = visual[b,i,:].v1[b] + 257*pos[b,i,:].v2[b] - S[b].v2[b] + c[b]
// ---------------------------------------------------------------------------
__global__ __launch_bounds__(256) void kC(
    const float* __restrict__ visual, // [B][N][DV]
    const float* __restrict__ pos,    // [B][N][DP]
    const float* __restrict__ v,      // [B][DK]
    const float* __restrict__ S,      // [B][DP]
    const float* __restrict__ c,      // [B]
    float* __restrict__ out)          // [B][N]
{
    const int t    = threadIdx.x;
    const int wave = t >> 6;
    const int lane = t & 63;
    const int R0   = blockIdx.x * 8 + wave * 2;
    const int b    = R0 >> 8;
    const int i0   = R0 & 255;

    const float4* vb = (const float4*)(v + (size_t)b * DK_);
    const float4* v0 = (const float4*)(visual + ((size_t)b * N_ + i0) * DV_);

    float a0 = 0.f, a1 = 0.f;
    #pragma unroll
    for (int j = 0; j < 8; ++j) {
        const int idx = lane + 64 * j;
        const float4 wv = vb[idx];
        const float4 x0 = v0[idx];
        const float4 x1 = v0[idx + 512];
        a0 = fmaf(x0.x, wv.x, a0); a0 = fmaf(x0.y, wv.y, a0);
        a0 = fmaf(x0.z, wv.z, a0); a0 = fmaf(x0.w, wv.w, a0);
        a1 = fmaf(x1.x, wv.x, a1); a1 = fmaf(x1.y, wv.y, a1);
        a1 = fmaf(x1.z, wv.z, a1); a1 = fmaf(x1.w, wv.w, a1);
    }
    #pragma unroll
    for (int off = 1; off < 64; off <<= 1) {
        a0 += __shfl_xor(a0, off, 64);
        a1 += __shfl_xor(a1, off, 64);
    }

    if (lane < 2) {
        const float accq = (lane == 0) ? a0 : a1;
        const int i = i0 + lane;
        const float* v2 = v + (size_t)b * DK_ + DV_;
        const float* pr = pos + ((size_t)b * N_ + i) * DP_;
        const float* Sb = S + b * DP_;
        float pd = 0.f, sd = 0.f;
        #pragma unroll
        for (int d = 0; d < DP_; ++d) {
            pd = fmaf(pr[d], v2[d], pd);
            sd = fmaf(Sb[d], v2[d], sd);
        }
        out[(size_t)b * N_ + i] = accq + 257.f * pd - sd + c[b];
    }
}

// ---------------------------------------------------------------------------
extern "C" void kernel_launch(void* const* d_in, const int* in_sizes, int n_in,
                              void* d_out, int out_size, void* d_ws, size_t ws_size,
                              hipStream_t stream) {
    const float* visual   = (const float*)d_in[0];
    const float* position = (const float*)d_in[1];
    const float* text     = (const float*)d_in[2];
    const float* Wt       = (const float*)d_in[3];
    const float* bt       = (const float*)d_in[4];
    const float* Wo       = (const float*)d_in[5];
    const float* bo       = (const float*)d_in[6];
    const float* Wa       = (const float*)d_in[7];
    const float* ba       = (const float*)d_in[8];
    float* out = (float*)d_out;

    float* ws = (float*)d_ws;
    float* wT = ws + WS_WT;
    float* S  = ws + WS_S;
    float* c  = ws + WS_C;
    float* v  = ws + WS_V;

    kA<<<256, 256, 0, stream>>>(position, text, Wt, bt, Wa, wT, S);
    kB<<<515, 256, 0, stream>>>(Wo, bo, ba, wT, v, c);
    kC<<<2048, 256, 0, stream>>>(visual, position, v, S, c, out);
}